// Round 3
// baseline (5682.253 us; speedup 1.0000x reference)
//
#include <hip/hip_runtime.h>

// ---------------------------------------------------------------------------
// Seq2Seq: encoder LSTM (128 steps) -> decoder LSTM (127 steps) -> FC to vocab
// B=32, S=T=128, V=32000, E=H=256
//
// R3: lstm_batch was per-CU L1-port bound (1 MB fp32 Whh streamed per step =
// 7.8 us/step). Fix: bf16 weights resident in the CU -- 256 KB in VGPRs
// (64 regs/thread x 1024 thr) + 144 KB in LDS + only 112 KB/step streamed
// from L2. New floor is VALU (~1.9 us/step).
// ---------------------------------------------------------------------------

typedef __attribute__((ext_vector_type(8))) short bf16x8;
typedef __attribute__((ext_vector_type(4))) float f32x4;
typedef __attribute__((ext_vector_type(8))) unsigned short u16x8;
typedef __attribute__((ext_vector_type(4))) unsigned int u32x4;

// workspace byte offsets (all 256-aligned)
#define WS_XG_E   0u          // 128*32*1024 f32 = 16,777,216 B
#define WS_XG_D   16777216u   // 127*32*1024 f32 = 16,646,144 B
#define WS_FCW    33423360u   // 32000*256 bf16  = 16,384,000 B
#define WS_HS     49807360u   // 4064*256 bf16   =  2,080,768 B
#define WS_WTE    51888128u   // 1024*256 bf16   =    524,288 B
#define WS_WTD    52936704u   // 1024*256 bf16   =    524,288 B

__device__ __forceinline__ unsigned short f2bf(float f) {
  unsigned u = __float_as_uint(f);
  u += 0x7FFFu + ((u >> 16) & 1u);   // round-to-nearest-even
  return (unsigned short)(u >> 16);
}

__device__ __forceinline__ float sigf(float x) {
  float e = __expf(-x);
  return __builtin_amdgcn_rcpf(1.f + e);
}
__device__ __forceinline__ float tanh_fast(float x) {
  float e = __expf(-2.f * x);
  return fmaf(2.f, __builtin_amdgcn_rcpf(1.f + e), -1.f);  // (1-e)/(1+e)
}

// 8 bf16 weights (one k8 block) dotted against 8 wave-uniform h values.
__device__ __forceinline__ void acc8(const bf16x8 w, const float4 ha,
                                     const float4 hb, float& g0, float& g1,
                                     float& g2, float& g3) {
  u32x4 u = __builtin_bit_cast(u32x4, w);
  g0 = fmaf(__uint_as_float(u.x << 16), ha.x, g0);
  g1 = fmaf(__uint_as_float(u.x & 0xFFFF0000u), ha.y, g1);
  g2 = fmaf(__uint_as_float(u.y << 16), ha.z, g2);
  g3 = fmaf(__uint_as_float(u.y & 0xFFFF0000u), ha.w, g3);
  g0 = fmaf(__uint_as_float(u.z << 16), hb.x, g0);
  g1 = fmaf(__uint_as_float(u.z & 0xFFFF0000u), hb.y, g1);
  g2 = fmaf(__uint_as_float(u.w << 16), hb.z, g2);
  g3 = fmaf(__uint_as_float(u.w & 0xFFFF0000u), hb.w, g3);
}

// ---------------------------------------------------------------------------
__global__ __launch_bounds__(256) void zero_col0(float* __restrict__ out) {
  int i = blockIdx.x * 256 + threadIdx.x;        // 256,000 float4s total
  int b = i / 8000;
  int r = i - b * 8000;
  float4 z; z.x = 0.f; z.y = 0.f; z.z = 0.f; z.w = 0.f;
  ((float4*)out)[b * 1024000 + r] = z;           // out[b][0][v]
}

__global__ __launch_bounds__(256) void cvt_bf16(const float* __restrict__ in,
                                                unsigned short* __restrict__ o,
                                                int n4) {
  int i = blockIdx.x * 256 + threadIdx.x;
  if (i < n4) {
    float4 v = ((const float4*)in)[i];
    ushort4 u;
    u.x = f2bf(v.x); u.y = f2bf(v.y); u.z = f2bf(v.z); u.w = f2bf(v.w);
    *(ushort4*)(o + i * 4) = u;
  }
}

// Whh[1024 r][256 k] -> bf16 T[k8][1024 r][8 j]: T[((k8*1024)+r)*8+j] =
// bf16(W[r*256 + k8*8 + j]). Wave loads of T are 1KB contiguous (lane = r).
__global__ __launch_bounds__(256) void prep_wbf(const float* __restrict__ We,
                                                const float* __restrict__ Wd,
                                                unsigned short* __restrict__ Te,
                                                unsigned short* __restrict__ Td) {
  int d = blockIdx.x * 256 + threadIdx.x;       // 0..262143
  const float* W = blockIdx.y ? Wd : We;
  unsigned short* T = blockIdx.y ? Td : Te;
  int j = d & 7, r = (d >> 3) & 1023, k8 = d >> 13;
  T[d] = f2bf(W[r * 256 + k8 * 8 + j]);
}

// ---------------------------------------------------------------------------
// xg[row][n] = emb[token(row)] @ Wih^T + bias ; row = t*32 + b
__global__ __launch_bounds__(256) void xg_gemm(
    const int* __restrict__ tok, const float* __restrict__ emb,
    const float* __restrict__ Wih, const float* __restrict__ bias,
    float* __restrict__ xg, const int Mrows) {
  __shared__ unsigned short As[128][264];  // +8 bf16 pad -> 2-way (free)
  __shared__ unsigned short Bs[128][264];
  const int tid = threadIdx.x;
  const int nb = blockIdx.x, rb = blockIdx.y;
  {
    int lr = tid >> 1, half = tid & 1;
    int cb = half * 128;
    int row = rb * 128 + lr;
    int rowc = row < Mrows ? row : (Mrows - 1);
    int tt = rowc >> 5, bb = rowc & 31;
    int tk = tok[bb * 128 + tt];
    const float4* sa = (const float4*)(emb + tk * 256 + cb);
    const float4* sb = (const float4*)(Wih + (nb * 128 + lr) * 256 + cb);
#pragma unroll
    for (int i = 0; i < 32; ++i) {
      float4 v = sa[i];
      ushort4 u;
      u.x = f2bf(v.x); u.y = f2bf(v.y); u.z = f2bf(v.z); u.w = f2bf(v.w);
      *(ushort4*)&As[lr][cb + i * 4] = u;
      float4 v2 = sb[i];
      ushort4 u2;
      u2.x = f2bf(v2.x); u2.y = f2bf(v2.y); u2.z = f2bf(v2.z); u2.w = f2bf(v2.w);
      *(ushort4*)&Bs[lr][cb + i * 4] = u2;
    }
  }
  __syncthreads();
  const int lane = tid & 63, w = tid >> 6;
  const int wr = w >> 1, wc = w & 1;
  const int fr = lane & 15, kg = lane >> 4;
  f32x4 acc[4][4];
  const f32x4 zero = {0.f, 0.f, 0.f, 0.f};
#pragma unroll
  for (int mi = 0; mi < 4; ++mi)
#pragma unroll
    for (int ni = 0; ni < 4; ++ni) acc[mi][ni] = zero;
#pragma unroll
  for (int ks = 0; ks < 8; ++ks) {
    const int kb = ks * 32 + kg * 8;
    bf16x8 a[4], b[4];
#pragma unroll
    for (int mi = 0; mi < 4; ++mi)
      a[mi] = *(const bf16x8*)&As[wr * 64 + mi * 16 + fr][kb];
#pragma unroll
    for (int ni = 0; ni < 4; ++ni)
      b[ni] = *(const bf16x8*)&Bs[wc * 64 + ni * 16 + fr][kb];
#pragma unroll
    for (int mi = 0; mi < 4; ++mi)
#pragma unroll
      for (int ni = 0; ni < 4; ++ni)
        acc[mi][ni] = __builtin_amdgcn_mfma_f32_16x16x32_bf16(a[mi], b[ni], acc[mi][ni], 0, 0, 0);
  }
#pragma unroll
  for (int ni = 0; ni < 4; ++ni) {
    const int colg = nb * 128 + wc * 64 + ni * 16 + fr;
    const float bv = bias[colg];
#pragma unroll
    for (int mi = 0; mi < 4; ++mi) {
#pragma unroll
      for (int r = 0; r < 4; ++r) {
        int rowg = rb * 128 + wr * 64 + mi * 16 + kg * 4 + r;
        if (rowg < Mrows) xg[rowg * 1024 + colg] = acc[mi][ni][r] + bv;
      }
    }
  }
}

// ---------------------------------------------------------------------------
// Per-batch LSTM chain. Block b (32 blocks x 1024 thr): thread r owns gate
// row r. Weights bf16: k8 0..15 in VGPRs, 16..24 in LDS, 25..31 streamed
// from L2 each step. h broadcast from LDS (wave-uniform b128 reads).
__global__ __launch_bounds__(1024) void lstm_batch(
    const unsigned short* __restrict__ WTe, const unsigned short* __restrict__ WTd,
    const float* __restrict__ xgE, const float* __restrict__ xgD,
    unsigned short* __restrict__ hs) {
  __shared__ __align__(16) float hlds[256];
  __shared__ float glds[1024];
  __shared__ __align__(16) unsigned short wl[73728];  // 9 k8 x 1024 r x 8 = 144 KB
  const int tid = threadIdx.x;
  const int b = blockIdx.x;
  float c = 0.f;
  if (tid < 256) hlds[tid] = 0.f;

  for (int phase = 0; phase < 2; ++phase) {
    const unsigned short* WT = phase ? WTd : WTe;
    const float* xg = phase ? xgD : xgE;
    const int steps = phase ? 127 : 128;
    const bf16x8* wsrc = (const bf16x8*)WT + tid;
    // 16 k8 blocks -> 64 VGPRs of persistent weights
    bf16x8 wreg[16];
#pragma unroll
    for (int k8 = 0; k8 < 16; ++k8) wreg[k8] = wsrc[k8 * 1024];
    __syncthreads();  // prev phase's last dot fully done before wl overwrite
    {
      bf16x8* ld = (bf16x8*)wl + tid;
#pragma unroll
      for (int k8 = 0; k8 < 9; ++k8) ld[k8 * 1024] = wsrc[(16 + k8) * 1024];
    }
    const bf16x8* wsp = wsrc + 25 * 1024;

    for (int t = 0; t < steps; ++t) {
      // issue the streamed 7 k8 (L2-resident, no LDS dependence) early
      bf16x8 wstr[7];
#pragma unroll
      for (int i = 0; i < 7; ++i) wstr[i] = wsp[i * 1024];
      __syncthreads();          // hlds from prev step ready (wl on t==0)
      float x0, x1, x2, x3;
      if (tid < 256) {          // prefetch xg
        const float* xr = xg + (t * 32 + b) * 1024 + tid;
        x0 = xr[0]; x1 = xr[256]; x2 = xr[512]; x3 = xr[768];
      }
      const float4* hp = (const float4*)hlds;
      float g0 = 0.f, g1 = 0.f, g2 = 0.f, g3 = 0.f;
#pragma unroll
      for (int k8 = 0; k8 < 16; ++k8)
        acc8(wreg[k8], hp[2 * k8], hp[2 * k8 + 1], g0, g1, g2, g3);
      const bf16x8* wlp = (const bf16x8*)wl + tid;
#pragma unroll
      for (int k8 = 0; k8 < 9; ++k8)
        acc8(wlp[k8 * 1024], hp[32 + 2 * k8], hp[33 + 2 * k8], g0, g1, g2, g3);
#pragma unroll
      for (int i = 0; i < 7; ++i)
        acc8(wstr[i], hp[50 + 2 * i], hp[51 + 2 * i], g0, g1, g2, g3);
      glds[tid] = (g0 + g1) + (g2 + g3);
      __syncthreads();
      if (tid < 256) {
        float gi = x0 + glds[tid];
        float gf = x1 + glds[256 + tid];
        float gg = x2 + glds[512 + tid];
        float go = x3 + glds[768 + tid];
        c = sigf(gf) * c + sigf(gi) * tanh_fast(gg);
        float h = sigf(go) * tanh_fast(c);
        hlds[tid] = h;
        if (phase) hs[(t * 32 + b) * 256 + tid] = f2bf(h);
      }
    }
  }
}

// ---------------------------------------------------------------------------
// FC: out[b][t+1][v] = hs[t*32+b][:] . fc_W[v][:] + fc_b[v]
__global__ __launch_bounds__(256) void fc_gemm(
    const unsigned short* __restrict__ hsb, const unsigned short* __restrict__ fwb,
    const float* __restrict__ fcb, float* __restrict__ out) {
  __shared__ unsigned short As[128][264];
  __shared__ unsigned short Bs[128][264];
  const int tid = threadIdx.x;
  const int nb = blockIdx.x, rb = blockIdx.y;
  {
    int lr = tid >> 1, half = tid & 1;
    int cb = half * 128;
    int row = rb * 128 + lr;
    if (row < 4064) {
      const u16x8* s = (const u16x8*)(hsb + row * 256 + cb);
#pragma unroll
      for (int i = 0; i < 16; ++i) *(u16x8*)&As[lr][cb + i * 8] = s[i];
    } else {
      u16x8 z = {0, 0, 0, 0, 0, 0, 0, 0};
#pragma unroll
      for (int i = 0; i < 16; ++i) *(u16x8*)&As[lr][cb + i * 8] = z;
    }
    const u16x8* s2 = (const u16x8*)(fwb + (nb * 128 + lr) * 256 + cb);
#pragma unroll
    for (int i = 0; i < 16; ++i) *(u16x8*)&Bs[lr][cb + i * 8] = s2[i];
  }
  __syncthreads();
  const int lane = tid & 63, w = tid >> 6;
  const int wr = w >> 1, wc = w & 1;
  const int fr = lane & 15, kg = lane >> 4;
  f32x4 acc[4][4];
  const f32x4 zero = {0.f, 0.f, 0.f, 0.f};
#pragma unroll
  for (int mi = 0; mi < 4; ++mi)
#pragma unroll
    for (int ni = 0; ni < 4; ++ni) acc[mi][ni] = zero;
#pragma unroll
  for (int ks = 0; ks < 8; ++ks) {
    const int kb = ks * 32 + kg * 8;
    bf16x8 a[4], b[4];
#pragma unroll
    for (int mi = 0; mi < 4; ++mi)
      a[mi] = *(const bf16x8*)&As[wr * 64 + mi * 16 + fr][kb];
#pragma unroll
    for (int ni = 0; ni < 4; ++ni)
      b[ni] = *(const bf16x8*)&Bs[wc * 64 + ni * 16 + fr][kb];
#pragma unroll
    for (int mi = 0; mi < 4; ++mi)
#pragma unroll
      for (int ni = 0; ni < 4; ++ni)
        acc[mi][ni] = __builtin_amdgcn_mfma_f32_16x16x32_bf16(a[mi], b[ni], acc[mi][ni], 0, 0, 0);
  }
#pragma unroll
  for (int ni = 0; ni < 4; ++ni) {
    const int colg = nb * 128 + wc * 64 + ni * 16 + fr;
    const float bv = fcb[colg];
#pragma unroll
    for (int mi = 0; mi < 4; ++mi) {
#pragma unroll
      for (int r = 0; r < 4; ++r) {
        int rowg = rb * 128 + wr * 64 + mi * 16 + kg * 4 + r;
        if (rowg < 4064) {
          int tt = rowg >> 5, bb = rowg & 31;
          out[(bb * 128 + tt + 1) * 32000 + colg] = acc[mi][ni][r] + bv;
        }
      }
    }
  }
}

// ---------------------------------------------------------------------------
extern "C" void kernel_launch(void* const* d_in, const int* in_sizes, int n_in,
                              void* d_out, int out_size, void* d_ws, size_t ws_size,
                              hipStream_t stream) {
  const int* src = (const int*)d_in[0];
  const int* tgt = (const int*)d_in[1];
  const float* enc_emb = (const float*)d_in[2];
  const float* enc_Wih = (const float*)d_in[3];
  const float* enc_Whh = (const float*)d_in[4];
  const float* enc_b = (const float*)d_in[5];
  const float* dec_emb = (const float*)d_in[6];
  const float* dec_Wih = (const float*)d_in[7];
  const float* dec_Whh = (const float*)d_in[8];
  const float* dec_b = (const float*)d_in[9];
  const float* fc_W = (const float*)d_in[10];
  const float* fc_b = (const float*)d_in[11];
  float* out = (float*)d_out;
  char* ws = (char*)d_ws;

  float* xg_e = (float*)(ws + WS_XG_E);
  float* xg_d = (float*)(ws + WS_XG_D);
  unsigned short* fcw = (unsigned short*)(ws + WS_FCW);
  unsigned short* hs = (unsigned short*)(ws + WS_HS);
  unsigned short* wte = (unsigned short*)(ws + WS_WTE);
  unsigned short* wtd = (unsigned short*)(ws + WS_WTD);

  zero_col0<<<1000, 256, 0, stream>>>(out);
  cvt_bf16<<<8000, 256, 0, stream>>>(fc_W, fcw, 2048000);
  prep_wbf<<<dim3(1024, 2), 256, 0, stream>>>(enc_Whh, dec_Whh, wte, wtd);
  xg_gemm<<<dim3(8, 32), 256, 0, stream>>>(src, enc_emb, enc_Wih, enc_b, xg_e, 4096);
  xg_gemm<<<dim3(8, 32), 256, 0, stream>>>(tgt, dec_emb, dec_Wih, dec_b, xg_d, 4064);
  lstm_batch<<<32, 1024, 0, stream>>>(wte, wtd, xg_e, xg_d, hs);
  fc_gemm<<<dim3(250, 32), 256, 0, stream>>>(hs, fcw, fc_b, out);
}

// Round 4
// 1005.124 us; speedup vs baseline: 5.6533x; 5.6533x over previous
//
#include <hip/hip_runtime.h>

// ---------------------------------------------------------------------------
// Seq2Seq: encoder LSTM (128 steps) -> decoder LSTM (127 steps) -> FC to vocab
// B=32, S=T=128, V=32000, E=H=256
//
// R4: R3's regression was a spill (VGPR_Count=64 with launch_bounds(1024):
// compiler targeted 2 blocks/CU and spilled wreg[16] to scratch -> 77 MB
// writes/step-loop). Fix by construction: 512-thread blocks with
// __launch_bounds__(512, 2) -> 1 block/CU, 256-VGPR cap. Weights now f16,
// FULLY CU-resident: 192 VGPRs (24 k8 x 2 rows) + 128 KB LDS (8 k8).
// Dot products via v_dot2_f32_f16 (no unpack). Zero per-step streaming.
// ---------------------------------------------------------------------------

typedef __attribute__((ext_vector_type(8))) short bf16x8;
typedef __attribute__((ext_vector_type(4))) float f32x4;
typedef __attribute__((ext_vector_type(8))) unsigned short u16x8;
typedef __attribute__((ext_vector_type(4))) unsigned int u32x4;
typedef __attribute__((ext_vector_type(8))) _Float16 f16x8;
typedef __attribute__((ext_vector_type(2))) _Float16 h2;

// workspace byte offsets (all 256-aligned)
#define WS_XG_E   0u          // 128*32*1024 f32 = 16,777,216 B
#define WS_XG_D   16777216u   // 127*32*1024 f32 = 16,646,144 B
#define WS_FCW    33423360u   // 32000*256 bf16  = 16,384,000 B
#define WS_HS     49807360u   // 4064*256 bf16   =  2,080,768 B
#define WS_WTE    51888128u   // 1024*256 f16    =    524,288 B
#define WS_WTD    52936704u   // 1024*256 f16    =    524,288 B

#define K8_REG 24
#define K8_LDS 8

__device__ __forceinline__ unsigned short f2bf(float f) {
  unsigned u = __float_as_uint(f);
  u += 0x7FFFu + ((u >> 16) & 1u);   // round-to-nearest-even
  return (unsigned short)(u >> 16);
}

__device__ __forceinline__ float sigf(float x) {
  float e = __expf(-x);
  return __builtin_amdgcn_rcpf(1.f + e);
}
__device__ __forceinline__ float tanh_fast(float x) {
  float e = __expf(-2.f * x);
  return fmaf(2.f, __builtin_amdgcn_rcpf(1.f + e), -1.f);  // (1-e)/(1+e)
}

#if __has_builtin(__builtin_amdgcn_fdot2)
#define FDOT2(a, w, h) a = __builtin_amdgcn_fdot2(w, h, a, false)
#else
#define FDOT2(a, w, h) a = fmaf((float)w[0], (float)h[0], fmaf((float)w[1], (float)h[1], a))
#endif

// 8 f16 weights vs 8 f16 h values -> two accumulator chains
__device__ __forceinline__ void dot8(const u16x8 w, const u32x4 hbits,
                                     float& a0, float& a1) {
  f16x8 wv = __builtin_bit_cast(f16x8, w);
  f16x8 hv = __builtin_bit_cast(f16x8, hbits);
  h2 w0 = {wv[0], wv[1]}, w1 = {wv[2], wv[3]};
  h2 w2 = {wv[4], wv[5]}, w3 = {wv[6], wv[7]};
  h2 h0 = {hv[0], hv[1]}, h1 = {hv[2], hv[3]};
  h2 hc = {hv[4], hv[5]}, h3 = {hv[6], hv[7]};
  FDOT2(a0, w0, h0);
  FDOT2(a1, w1, h1);
  FDOT2(a0, w2, hc);
  FDOT2(a1, w3, h3);
}

// ---------------------------------------------------------------------------
__global__ __launch_bounds__(256) void zero_col0(float* __restrict__ out) {
  int i = blockIdx.x * 256 + threadIdx.x;        // 256,000 float4s total
  int b = i / 8000;
  int r = i - b * 8000;
  float4 z; z.x = 0.f; z.y = 0.f; z.z = 0.f; z.w = 0.f;
  ((float4*)out)[b * 1024000 + r] = z;           // out[b][0][v]
}

__global__ __launch_bounds__(256) void cvt_bf16(const float* __restrict__ in,
                                                unsigned short* __restrict__ o,
                                                int n4) {
  int i = blockIdx.x * 256 + threadIdx.x;
  if (i < n4) {
    float4 v = ((const float4*)in)[i];
    ushort4 u;
    u.x = f2bf(v.x); u.y = f2bf(v.y); u.z = f2bf(v.z); u.w = f2bf(v.w);
    *(ushort4*)(o + i * 4) = u;
  }
}

// Whh[1024 r][256 k] -> f16 T[k8][1024 r][8 j]: T[((k8*1024)+r)*8+j] =
// f16(W[r*256 + k8*8 + j]). Wave loads of T are 1KB contiguous (lane = r).
__global__ __launch_bounds__(256) void prep_whalf(const float* __restrict__ We,
                                                  const float* __restrict__ Wd,
                                                  unsigned short* __restrict__ Te,
                                                  unsigned short* __restrict__ Td) {
  int d = blockIdx.x * 256 + threadIdx.x;       // 0..262143
  const float* W = blockIdx.y ? Wd : We;
  unsigned short* T = blockIdx.y ? Td : Te;
  int j = d & 7, r = (d >> 3) & 1023, k8 = d >> 13;
  _Float16 v = (_Float16)W[r * 256 + k8 * 8 + j];
  T[d] = __builtin_bit_cast(unsigned short, v);
}

// ---------------------------------------------------------------------------
// xg[row][n] = emb[token(row)] @ Wih^T + bias ; row = t*32 + b
__global__ __launch_bounds__(256) void xg_gemm(
    const int* __restrict__ tok, const float* __restrict__ emb,
    const float* __restrict__ Wih, const float* __restrict__ bias,
    float* __restrict__ xg, const int Mrows) {
  __shared__ unsigned short As[128][264];  // +8 bf16 pad -> 2-way (free)
  __shared__ unsigned short Bs[128][264];
  const int tid = threadIdx.x;
  const int nb = blockIdx.x, rb = blockIdx.y;
  {
    int lr = tid >> 1, half = tid & 1;
    int cb = half * 128;
    int row = rb * 128 + lr;
    int rowc = row < Mrows ? row : (Mrows - 1);
    int tt = rowc >> 5, bb = rowc & 31;
    int tk = tok[bb * 128 + tt];
    const float4* sa = (const float4*)(emb + tk * 256 + cb);
    const float4* sb = (const float4*)(Wih + (nb * 128 + lr) * 256 + cb);
#pragma unroll
    for (int i = 0; i < 32; ++i) {
      float4 v = sa[i];
      ushort4 u;
      u.x = f2bf(v.x); u.y = f2bf(v.y); u.z = f2bf(v.z); u.w = f2bf(v.w);
      *(ushort4*)&As[lr][cb + i * 4] = u;
      float4 v2 = sb[i];
      ushort4 u2;
      u2.x = f2bf(v2.x); u2.y = f2bf(v2.y); u2.z = f2bf(v2.z); u2.w = f2bf(v2.w);
      *(ushort4*)&Bs[lr][cb + i * 4] = u2;
    }
  }
  __syncthreads();
  const int lane = tid & 63, w = tid >> 6;
  const int wr = w >> 1, wc = w & 1;
  const int fr = lane & 15, kg = lane >> 4;
  f32x4 acc[4][4];
  const f32x4 zero = {0.f, 0.f, 0.f, 0.f};
#pragma unroll
  for (int mi = 0; mi < 4; ++mi)
#pragma unroll
    for (int ni = 0; ni < 4; ++ni) acc[mi][ni] = zero;
#pragma unroll
  for (int ks = 0; ks < 8; ++ks) {
    const int kb = ks * 32 + kg * 8;
    bf16x8 a[4], b[4];
#pragma unroll
    for (int mi = 0; mi < 4; ++mi)
      a[mi] = *(const bf16x8*)&As[wr * 64 + mi * 16 + fr][kb];
#pragma unroll
    for (int ni = 0; ni < 4; ++ni)
      b[ni] = *(const bf16x8*)&Bs[wc * 64 + ni * 16 + fr][kb];
#pragma unroll
    for (int mi = 0; mi < 4; ++mi)
#pragma unroll
      for (int ni = 0; ni < 4; ++ni)
        acc[mi][ni] = __builtin_amdgcn_mfma_f32_16x16x32_bf16(a[mi], b[ni], acc[mi][ni], 0, 0, 0);
  }
#pragma unroll
  for (int ni = 0; ni < 4; ++ni) {
    const int colg = nb * 128 + wc * 64 + ni * 16 + fr;
    const float bv = bias[colg];
#pragma unroll
    for (int mi = 0; mi < 4; ++mi) {
#pragma unroll
      for (int r = 0; r < 4; ++r) {
        int rowg = rb * 128 + wr * 64 + mi * 16 + kg * 4 + r;
        if (rowg < Mrows) xg[rowg * 1024 + colg] = acc[mi][ni][r] + bv;
      }
    }
  }
}

// ---------------------------------------------------------------------------
// Per-batch LSTM chain. Block b (32 blocks x 512 thr, 1 block/CU): thread t
// owns gate rows t and t+512. Weights f16, fully CU-resident: k8 0..23 in
// VGPRs (192 regs), k8 24..31 in LDS (128 KB). h kept as f16 pairs in LDS,
// read wave-uniform (broadcast). 2 barriers/step, no global traffic.
__global__ __launch_bounds__(512, 2) void lstm_batch(
    const unsigned short* __restrict__ WTe, const unsigned short* __restrict__ WTd,
    const float* __restrict__ xgE, const float* __restrict__ xgD,
    unsigned short* __restrict__ hs) {
  __shared__ __align__(16) unsigned int hp2[128];            // h as f16x2
  __shared__ float glds[1024];
  __shared__ __align__(16) unsigned short wl[K8_LDS * 8192]; // 128 KB
  const int tid = threadIdx.x;   // 0..511
  const int b = blockIdx.x;
  const int rA = tid, rB = tid + 512;
  float c0 = 0.f, c1 = 0.f;      // tid<128: cell state for dims 2tid, 2tid+1
  if (tid < 128) hp2[tid] = 0u;

  for (int phase = 0; phase < 2; ++phase) {
    const unsigned short* WT = phase ? WTd : WTe;
    const float* xg = phase ? xgD : xgE;
    const int steps = phase ? 127 : 128;
    const u16x8* wsrc = (const u16x8*)WT;     // [k8*1024 + row]
    u16x8 wA[K8_REG], wB[K8_REG];
#pragma unroll
    for (int k8 = 0; k8 < K8_REG; ++k8) {
      wA[k8] = wsrc[k8 * 1024 + rA];
      wB[k8] = wsrc[k8 * 1024 + rB];
    }
    __syncthreads();   // prior phase's wl reads complete before overwrite
    {
      u16x8* ld = (u16x8*)wl;
#pragma unroll
      for (int k8 = 0; k8 < K8_LDS; ++k8) {
        ld[k8 * 1024 + rA] = wsrc[(K8_REG + k8) * 1024 + rA];
        ld[k8 * 1024 + rB] = wsrc[(K8_REG + k8) * 1024 + rB];
      }
    }
    __syncthreads();   // wl + hp2 visible

    for (int t = 0; t < steps; ++t) {
      float x0, x1, x2, x3, x4, x5, x6, x7;
      if (tid < 128) {   // prefetch xg for dims 2tid, 2tid+1 (global, indep)
        const float* xr = xg + (t * 32 + b) * 1024 + 2 * tid;
        float2 v0 = *(const float2*)(xr);
        float2 v1 = *(const float2*)(xr + 256);
        float2 v2 = *(const float2*)(xr + 512);
        float2 v3 = *(const float2*)(xr + 768);
        x0 = v0.x; x1 = v0.y; x2 = v1.x; x3 = v1.y;
        x4 = v2.x; x5 = v2.y; x6 = v3.x; x7 = v3.y;
      }
      const u32x4* hq = (const u32x4*)hp2;    // 32 x 8-h-value chunks
      float a0 = 0.f, a1 = 0.f, b0 = 0.f, b1 = 0.f;
#pragma unroll
      for (int k8 = 0; k8 < K8_REG; ++k8) {
        u32x4 hh = hq[k8];                    // wave-uniform -> broadcast
        dot8(wA[k8], hh, a0, a1);
        dot8(wB[k8], hh, b0, b1);
      }
      const u16x8* wlp = (const u16x8*)wl;
#pragma unroll
      for (int k8 = 0; k8 < K8_LDS; ++k8) {
        u32x4 hh = hq[K8_REG + k8];
        dot8(wlp[k8 * 1024 + rA], hh, a0, a1);
        dot8(wlp[k8 * 1024 + rB], hh, b0, b1);
      }
      glds[rA] = a0 + a1;
      glds[rB] = b0 + b1;
      __syncthreads();                        // gates ready; hp2 reads done
      if (tid < 128) {
        const int d0 = 2 * tid;
        float gi0 = x0 + glds[d0],       gi1 = x1 + glds[d0 + 1];
        float gf0 = x2 + glds[256 + d0], gf1 = x3 + glds[257 + d0];
        float gg0 = x4 + glds[512 + d0], gg1 = x5 + glds[513 + d0];
        float go0 = x6 + glds[768 + d0], go1 = x7 + glds[769 + d0];
        c0 = sigf(gf0) * c0 + sigf(gi0) * tanh_fast(gg0);
        c1 = sigf(gf1) * c1 + sigf(gi1) * tanh_fast(gg1);
        float h0 = sigf(go0) * tanh_fast(c0);
        float h1 = sigf(go1) * tanh_fast(c1);
        h2 hp; hp[0] = (_Float16)h0; hp[1] = (_Float16)h1;
        hp2[tid] = __builtin_bit_cast(unsigned, hp);
        if (phase) {
          unsigned pk = (unsigned)f2bf(h0) | ((unsigned)f2bf(h1) << 16);
          *(unsigned*)(hs + (t * 32 + b) * 256 + d0) = pk;
        }
      }
      __syncthreads();                        // h(t) visible for next step
    }
  }
}

// ---------------------------------------------------------------------------
// FC: out[b][t+1][v] = hs[t*32+b][:] . fc_W[v][:] + fc_b[v]
__global__ __launch_bounds__(256) void fc_gemm(
    const unsigned short* __restrict__ hsb, const unsigned short* __restrict__ fwb,
    const float* __restrict__ fcb, float* __restrict__ out) {
  __shared__ unsigned short As[128][264];
  __shared__ unsigned short Bs[128][264];
  const int tid = threadIdx.x;
  const int nb = blockIdx.x, rb = blockIdx.y;
  {
    int lr = tid >> 1, half = tid & 1;
    int cb = half * 128;
    int row = rb * 128 + lr;
    if (row < 4064) {
      const u16x8* s = (const u16x8*)(hsb + row * 256 + cb);
#pragma unroll
      for (int i = 0; i < 16; ++i) *(u16x8*)&As[lr][cb + i * 8] = s[i];
    } else {
      u16x8 z = {0, 0, 0, 0, 0, 0, 0, 0};
#pragma unroll
      for (int i = 0; i < 16; ++i) *(u16x8*)&As[lr][cb + i * 8] = z;
    }
    const u16x8* s2 = (const u16x8*)(fwb + (nb * 128 + lr) * 256 + cb);
#pragma unroll
    for (int i = 0; i < 16; ++i) *(u16x8*)&Bs[lr][cb + i * 8] = s2[i];
  }
  __syncthreads();
  const int lane = tid & 63, w = tid >> 6;
  const int wr = w >> 1, wc = w & 1;
  const int fr = lane & 15, kg = lane >> 4;
  f32x4 acc[4][4];
  const f32x4 zero = {0.f, 0.f, 0.f, 0.f};
#pragma unroll
  for (int mi = 0; mi < 4; ++mi)
#pragma unroll
    for (int ni = 0; ni < 4; ++ni) acc[mi][ni] = zero;
#pragma unroll
  for (int ks = 0; ks < 8; ++ks) {
    const int kb = ks * 32 + kg * 8;
    bf16x8 a[4], b[4];
#pragma unroll
    for (int mi = 0; mi < 4; ++mi)
      a[mi] = *(const bf16x8*)&As[wr * 64 + mi * 16 + fr][kb];
#pragma unroll
    for (int ni = 0; ni < 4; ++ni)
      b[ni] = *(const bf16x8*)&Bs[wc * 64 + ni * 16 + fr][kb];
#pragma unroll
    for (int mi = 0; mi < 4; ++mi)
#pragma unroll
      for (int ni = 0; ni < 4; ++ni)
        acc[mi][ni] = __builtin_amdgcn_mfma_f32_16x16x32_bf16(a[mi], b[ni], acc[mi][ni], 0, 0, 0);
  }
#pragma unroll
  for (int ni = 0; ni < 4; ++ni) {
    const int colg = nb * 128 + wc * 64 + ni * 16 + fr;
    const float bv = fcb[colg];
#pragma unroll
    for (int mi = 0; mi < 4; ++mi) {
#pragma unroll
      for (int r = 0; r < 4; ++r) {
        int rowg = rb * 128 + wr * 64 + mi * 16 + kg * 4 + r;
        if (rowg < 4064) {
          int tt = rowg >> 5, bb = rowg & 31;
          out[(bb * 128 + tt + 1) * 32000 + colg] = acc[mi][ni][r] + bv;
        }
      }
    }
  }
}

// ---------------------------------------------------------------------------
extern "C" void kernel_launch(void* const* d_in, const int* in_sizes, int n_in,
                              void* d_out, int out_size, void* d_ws, size_t ws_size,
                              hipStream_t stream) {
  const int* src = (const int*)d_in[0];
  const int* tgt = (const int*)d_in[1];
  const float* enc_emb = (const float*)d_in[2];
  const float* enc_Wih = (const float*)d_in[3];
  const float* enc_Whh = (const float*)d_in[4];
  const float* enc_b = (const float*)d_in[5];
  const float* dec_emb = (const float*)d_in[6];
  const float* dec_Wih = (const float*)d_in[7];
  const float* dec_Whh = (const float*)d_in[8];
  const float* dec_b = (const float*)d_in[9];
  const float* fc_W = (const float*)d_in[10];
  const float* fc_b = (const float*)d_in[11];
  float* out = (float*)d_out;
  char* ws = (char*)d_ws;

  float* xg_e = (float*)(ws + WS_XG_E);
  float* xg_d = (float*)(ws + WS_XG_D);
  unsigned short* fcw = (unsigned short*)(ws + WS_FCW);
  unsigned short* hs = (unsigned short*)(ws + WS_HS);
  unsigned short* wte = (unsigned short*)(ws + WS_WTE);
  unsigned short* wtd = (unsigned short*)(ws + WS_WTD);

  zero_col0<<<1000, 256, 0, stream>>>(out);
  cvt_bf16<<<8000, 256, 0, stream>>>(fc_W, fcw, 2048000);
  prep_whalf<<<dim3(1024, 2), 256, 0, stream>>>(enc_Whh, dec_Whh, wte, wtd);
  xg_gemm<<<dim3(8, 32), 256, 0, stream>>>(src, enc_emb, enc_Wih, enc_b, xg_e, 4096);
  xg_gemm<<<dim3(8, 32), 256, 0, stream>>>(tgt, dec_emb, dec_Wih, dec_b, xg_d, 4064);
  lstm_batch<<<32, 512, 0, stream>>>(wte, wtd, xg_e, xg_d, hs);
  fc_gemm<<<dim3(250, 32), 256, 0, stream>>>(hs, fcw, fc_b, out);
}